// Round 10
// baseline (263.058 us; speedup 1.0000x reference)
//
#include <hip/hip_runtime.h>
#include <stdint.h>
#include <stddef.h>

using short8 = __attribute__((ext_vector_type(8))) short;
using short4v = __attribute__((ext_vector_type(4))) short;
using f32x4  = __attribute__((ext_vector_type(4))) float;
using f32x16 = __attribute__((ext_vector_type(16))) float;
using bf16x8 = __attribute__((ext_vector_type(8))) __bf16;

#define DEVI __device__ __forceinline__

// round-to-nearest-even fp32 -> bf16 (bit pattern as short)
DEVI short bf16r(float f) {
  union { float f; uint32_t u; } x; x.f = f;
  uint32_t r = x.u + 0x7FFFu + ((x.u >> 16) & 1u);
  return (short)(r >> 16);
}

DEVI f32x4 mfma16(short8 a, short8 b, f32x4 c) {
  return __builtin_amdgcn_mfma_f32_16x16x32_bf16(
      __builtin_bit_cast(bf16x8, a), __builtin_bit_cast(bf16x8, b), c, 0, 0, 0);
}

DEVI f32x16 mfma32(short8 a, short8 b, f32x16 c) {
  return __builtin_amdgcn_mfma_f32_32x32x16_bf16(
      __builtin_bit_cast(bf16x8, a), __builtin_bit_cast(bf16x8, b), c, 0, 0, 0);
}

DEVI void gload_lds16(const void* g, void* l) {
  __builtin_amdgcn_global_load_lds(
      (const void __attribute__((address_space(1)))*)g,
      (void __attribute__((address_space(3)))*)l,
      16, 0, 0);
}

// v_exp_f32 computes 2^x
DEVI float fexp2(float x) {
  float r;
  asm("v_exp_f32 %0, %1" : "=v"(r) : "v"(x));
  return r;
}

// packed fp32->bf16: dst[15:0]=bf16(a), dst[31:16]=bf16(b)
DEVI unsigned cvtpk(float a, float b) {
  unsigned r;
  asm("v_cvt_pk_bf16_f32 %0, %1, %2" : "=v"(r) : "v"(a), "v"(b));
  return r;
}

// ---------------- fp32 -> bf16 conversion (dual-segment: z selects) ----------------
__global__ void k_cvt2(const float* __restrict__ s0, short* __restrict__ d0,
                       const float* __restrict__ s1, short* __restrict__ d1, int n4) {
  const float* s = blockIdx.z ? s1 : s0;
  short* d = blockIdx.z ? d1 : d0;
  int i = blockIdx.x * blockDim.x + threadIdx.x;
  if (i < n4) {
    f32x4 v = reinterpret_cast<const f32x4*>(s)[i];
    short4v o;
    o[0] = bf16r(v[0]); o[1] = bf16r(v[1]); o[2] = bf16r(v[2]); o[3] = bf16r(v[3]);
    reinterpret_cast<short4v*>(d)[i] = o;
  }
}

__global__ void k_cvt(const float* __restrict__ src, short* __restrict__ dst, int n4) {
  int i = blockIdx.x * blockDim.x + threadIdx.x;
  if (i < n4) {
    f32x4 v = reinterpret_cast<const f32x4*>(src)[i];
    short4v o;
    o[0] = bf16r(v[0]); o[1] = bf16r(v[1]); o[2] = bf16r(v[2]); o[3] = bf16r(v[3]);
    reinterpret_cast<short4v*>(dst)[i] = o;
  }
}

// ---------------- GEMM: C(M,N) = (A(M,K)bf16 @ W(N,K)^T + bias) * alpha ----------------
// [R9 verbatim — green]
template<bool OUT_F32, bool DUAL>
__global__ __launch_bounds__(256) void k_gemm(
    const short* __restrict__ Aw, const short* __restrict__ Bw,
    const float* __restrict__ bias, void* __restrict__ Cp,
    const short* __restrict__ Aw2, const short* __restrict__ Bw2,
    const float* __restrict__ bias2, void* __restrict__ Cp2,
    int M, int N, int K, float alpha)
{
  if constexpr (DUAL) {
    if (blockIdx.z) { Aw = Aw2; Bw = Bw2; bias = bias2; Cp = Cp2; }
  }
  __shared__ short As[2][128 * 64];
  __shared__ short Bs[2][128 * 64];
  const int t = threadIdx.x;
  const int lane = t & 63;
  const int wid = t >> 6;
  const int wr = wid >> 1, wc = wid & 1;
  const int bm = blockIdx.y * 128;
  const int bn = blockIdx.x * 128;

  f32x4 acc[4][4];
  #pragma unroll
  for (int i = 0; i < 4; ++i)
    #pragma unroll
    for (int j = 0; j < 4; ++j) acc[i][j] = f32x4{0.f, 0.f, 0.f, 0.f};

  const int nt = K >> 6;

  auto stage = [&](const short* G, short (&buf)[128 * 64], int k0) {
    #pragma unroll
    for (int i = 0; i < 4; ++i) {
      int lin = t * 16 + i * 4096;
      int a = lin ^ (((lin >> 7) & 7) << 4);
      int row = a >> 7;
      int col = (a & 127) >> 1;
      const short* g = G + (size_t)row * K + k0 + col;
      gload_lds16(g, (char*)(&buf[0]) + (wid << 10) + (i << 12));
    }
  };

  stage(Aw + (size_t)bm * K, As[0], 0);
  stage(Bw + (size_t)bn * K, Bs[0], 0);
  __syncthreads();

  int cur = 0;
  for (int kt = 0; kt < nt; ++kt) {
    const bool pf = (kt + 1 < nt);
    if (pf) {
      stage(Aw + (size_t)bm * K, As[cur ^ 1], (kt + 1) << 6);
      stage(Bw + (size_t)bn * K, Bs[cur ^ 1], (kt + 1) << 6);
    }
    #pragma unroll
    for (int kk = 0; kk < 2; ++kk) {
      const int kb = (kk * 32 + ((lane >> 4) << 3)) << 1;
      short8 af[4], bfr[4];
      #pragma unroll
      for (int i = 0; i < 4; ++i) {
        int row = wr * 64 + i * 16 + (lane & 15);
        int byte = ((row << 7) + kb) ^ ((row & 7) << 4);
        af[i] = *reinterpret_cast<const short8*>((const char*)(&As[cur][0]) + byte);
      }
      #pragma unroll
      for (int j = 0; j < 4; ++j) {
        int row = wc * 64 + j * 16 + (lane & 15);
        int byte = ((row << 7) + kb) ^ ((row & 7) << 4);
        bfr[j] = *reinterpret_cast<const short8*>((const char*)(&Bs[cur][0]) + byte);
      }
      __builtin_amdgcn_s_setprio(1);
      #pragma unroll
      for (int i = 0; i < 4; ++i)
        #pragma unroll
        for (int j = 0; j < 4; ++j)
          acc[i][j] = mfma16(af[i], bfr[j], acc[i][j]);
      __builtin_amdgcn_s_setprio(0);
    }
    __syncthreads();
    cur ^= 1;
  }

  #pragma unroll
  for (int j = 0; j < 4; ++j) {
    int col = bn + wc * 64 + j * 16 + (lane & 15);
    float bv = bias[col];
    #pragma unroll
    for (int i = 0; i < 4; ++i) {
      int row0 = bm + wr * 64 + i * 16 + ((lane >> 4) << 2);
      #pragma unroll
      for (int r = 0; r < 4; ++r) {
        float v = (acc[i][j][r] + bv) * alpha;
        if constexpr (OUT_F32)
          ((float*)Cp)[(size_t)(row0 + r) * N + col] = v;
        else
          ((short*)Cp)[(size_t)(row0 + r) * N + col] = bf16r(v);
      }
    }
  }
}

// ---------------- flash attention, 8-warp swapped-QK^T, S-AHEAD PIPELINE ----------------
// Numerics IDENTICAL to R3/R8/R9 (defer-max softmax, same pack, same per-tile order:
// PV(t-1) lands in o before tile-t rescale). Only instruction order + buffer rings change:
//   body(t): stage(t+1) issue | PV(t-1) MFMA | softmax(S_t) VALU (overlaps PV)
//            | writeV(t+1) | barrier | S_{t+1} = QK^T (consumed after next PV)
// V is a 3-ring (PV(t-1) read vs V(t+1) write), K stays 2-ring. Ring safety: every
// buffer's reader precedes its overwriter by >= 1 barrier (verified t-indices).
// NOTE: fixed-m=0 softmax in this structure fails (R5-R7, ~0.04) — keep defer-max.
__global__ __launch_bounds__(512, 4) void k_attn(
    const short* __restrict__ Q, const short* __restrict__ Kg,
    const short* __restrict__ Vg, short* __restrict__ Op)
{
  constexpr int T = 2048;
  constexpr int NT = T / 64;

  const int orig = blockIdx.x;
  const int wgid = (orig & 7) * 64 + (orig >> 3);
  const int bh = wgid >> 3;
  const int qb = wgid & 7;
  const int b = bh >> 5, h = bh & 31;
  const int g = h >> 2;
  const int q0 = qb * 256;

  const int t = threadIdx.x;
  const int lane = t & 63;
  const int wid = t >> 6;
  const int lo = lane & 31;
  const int hi = lane >> 5;

  __shared__ alignas(16) union {
    struct {
      short Kl[2][64 * 64];   // [key][d], XOR-swizzled, gload_lds staged (2-ring)
      short Vt[3][64 * 72];   // [d][key], stride 72, reg-staged transpose (3-ring)
    } s;
    short Ol[8][32 * 72];     // epilogue O transpose, per-warp
  } sm;

  const size_t qrow = (size_t)(b * T + q0 + wid * 32 + lo);
  short8 qf[4];
  #pragma unroll
  for (int s = 0; s < 4; ++s)
    qf[s] = *reinterpret_cast<const short8*>(Q + qrow * 2048 + h * 64 + s * 16 + hi * 8);

  f32x16 o0, o1;
  #pragma unroll
  for (int r = 0; r < 16; ++r) { o0[r] = 0.f; o1[r] = 0.f; }
  float m = -10000.f, l = 0.f;

  const short* Kbase = Kg + (size_t)(b * T) * 512 + g * 64;
  const short* Vbase = Vg + (size_t)(b * T) * 512 + g * 64;

  auto stageK = [&](int buf, int k0) {
    int lin = t * 16;
    int a = lin ^ (((lin >> 7) & 7) << 4);
    int row = a >> 7;
    int col = (a & 127) >> 1;
    gload_lds16(Kbase + (size_t)(k0 + row) * 512 + col,
                (char*)(&sm.s.Kl[buf][0]) + (wid << 10));
  };
  short8 vreg;
  auto loadV = [&](int k0) {
    vreg = *reinterpret_cast<const short8*>(
        Vbase + (size_t)(k0 + lane) * 512 + wid * 8);
  };
  auto writeV = [&](int buf) {
    #pragma unroll
    for (int e = 0; e < 8; ++e)
      sm.s.Vt[buf][(wid * 8 + e) * 72 + lane] = vreg[e];
  };

  // pipeline state: S (one tile ahead), pb (P of current tile, consumed by next PV)
  f32x16 st0, st1;
  short8 pb[4];

  // QK^T of one tile from Kl[kbuf] -> st0/st1
  auto qkt = [&](int kbuf) {
    const char* base = (const char*)(&sm.s.Kl[kbuf][0]);
    #pragma unroll
    for (int r = 0; r < 16; ++r) { st0[r] = 0.f; st1[r] = 0.f; }
    {
      short8 kf[4];
      #pragma unroll
      for (int s = 0; s < 4; ++s) {
        int row = lo;
        int byte = ((row << 7) + (s << 5) + (hi << 4)) ^ ((row & 7) << 4);
        kf[s] = *reinterpret_cast<const short8*>(base + byte);
      }
      #pragma unroll
      for (int s = 0; s < 4; ++s) st0 = mfma32(kf[s], qf[s], st0);
    }
    {
      short8 kf[4];
      #pragma unroll
      for (int s = 0; s < 4; ++s) {
        int row = 32 + lo;
        int byte = ((row << 7) + (s << 5) + (hi << 4)) ^ ((row & 7) << 4);
        kf[s] = *reinterpret_cast<const short8*>(base + byte);
      }
      #pragma unroll
      for (int s = 0; s < 4; ++s) st1 = mfma32(kf[s], qf[s], st1);
    }
  };

  // online softmax (R3-verbatim math) + pack -> pb
  auto softmax_pack = [&]() {
    float mx = st0[0];
    #pragma unroll
    for (int r = 1; r < 16; ++r) mx = fmaxf(mx, st0[r]);
    #pragma unroll
    for (int r = 0; r < 16; ++r) mx = fmaxf(mx, st1[r]);
    mx = fmaxf(mx, __shfl_xor(mx, 32));
    if (!__all(mx - m <= 8.0f)) {      // T13 defer-max
      float mn = fmaxf(m, mx);
      float sc = fexp2(m - mn);
      m = mn; l *= sc;
      o0 = o0 * sc; o1 = o1 * sc;
    }
    float ssum = 0.f;
    #pragma unroll
    for (int r = 0; r < 16; ++r) { float e = fexp2(st0[r] - m); st0[r] = e; ssum += e; }
    #pragma unroll
    for (int r = 0; r < 16; ++r) { float e = fexp2(st1[r] - m); st1[r] = e; ssum += e; }
    ssum += __shfl_xor(ssum, 32);
    l += ssum;

    #pragma unroll
    for (int tt = 0; tt < 2; ++tt) {
      const f32x16& sv = tt ? st1 : st0;
      #pragma unroll
      for (int half = 0; half < 2; ++half) {
        unsigned x1 = cvtpk(sv[half * 8 + 0], sv[half * 8 + 1]);
        unsigned x2 = cvtpk(sv[half * 8 + 2], sv[half * 8 + 3]);
        unsigned x3 = cvtpk(sv[half * 8 + 4], sv[half * 8 + 5]);
        unsigned x4 = cvtpk(sv[half * 8 + 6], sv[half * 8 + 7]);
        unsigned y1 = __shfl_xor(x1, 32);
        unsigned y2 = __shfl_xor(x2, 32);
        unsigned y3 = __shfl_xor(x3, 32);
        unsigned y4 = __shfl_xor(x4, 32);
        union { unsigned u[4]; short8 s8; } p;
        p.u[0] = hi ? y3 : x1;
        p.u[1] = hi ? y4 : x2;
        p.u[2] = hi ? x3 : y1;
        p.u[3] = hi ? x4 : y2;
        pb[tt * 2 + half] = p.s8;
      }
    }
  };

  // PV of one tile from Vt[vbuf] using pb
  auto pv = [&](int vbuf) {
    const char* base = (const char*)(&sm.s.Vt[vbuf][0]);
    #pragma unroll
    for (int ks = 0; ks < 4; ++ks) {
      {
        int byte = (lo * 144) + (ks << 5) + (hi << 4);
        short8 va = *reinterpret_cast<const short8*>(base + byte);
        o0 = mfma32(va, pb[ks], o0);
      }
      {
        int byte = ((32 + lo) * 144) + (ks << 5) + (hi << 4);
        short8 va = *reinterpret_cast<const short8*>(base + byte);
        o1 = mfma32(va, pb[ks], o1);
      }
    }
  };

  // ---- prologue ----
  stageK(0, 0); loadV(0); writeV(0);
  __syncthreads();
  qkt(0);                       // S = tile 0
  stageK(1, 64); loadV(64);
  softmax_pack();               // pb = tile 0
  writeV(1);
  __syncthreads();
  qkt(1);                       // S = tile 1

  // ---- main loop: body(t) = PV(t-1) + softmax(t) + stage(t+1) + QKT(t+1) ----
  int rb = 0, wb = 2;           // V ring: read (t-1)%3, write (t+1)%3
  for (int kt = 1; kt < NT; ++kt) {
    const bool pf = (kt + 1 < NT);
    if (pf) { stageK((kt + 1) & 1, (kt + 1) * 64); loadV((kt + 1) * 64); }
    pv(rb);                     // tile kt-1 into o (before tile-kt rescale — order == R3)
    softmax_pack();             // tile kt (VALU; PV MFMAs in flight)
    if (pf) writeV(wb);
    __syncthreads();
    if (pf) qkt((kt + 1) & 1);  // S = tile kt+1; consumed only after next body's PV
    rb = (rb == 2) ? 0 : rb + 1;
    wb = (wb == 2) ? 0 : wb + 1;
  }
  pv(rb);                       // tile NT-1
  __syncthreads();              // Vt reads done before Ol alias reuse

  // ---- epilogue: normalize, transpose via LDS, coalesced store ----
  float inv = 1.0f / l;
  #pragma unroll
  for (int dt = 0; dt < 2; ++dt) {
    const f32x16& ov = dt ? o1 : o0;
    #pragma unroll
    for (int r = 0; r < 16; r += 2) {
      unsigned d2 = cvtpk(ov[r] * inv, ov[r + 1] * inv);
      int dpos = dt * 32 + (r & 3) + 8 * (r >> 2) + 4 * hi;
      *reinterpret_cast<unsigned*>((char*)(&sm.Ol[wid][0]) + (lo * 72 + dpos) * 2) = d2;
    }
  }
  __syncthreads();
  #pragma unroll
  for (int i = 0; i < 4; ++i) {
    int c = hi * 4 + i;
    short8 v = *reinterpret_cast<const short8*>((const char*)(&sm.Ol[wid][0]) + lo * 144 + c * 16);
    *reinterpret_cast<short8*>(Op + qrow * 2048 + h * 64 + c * 8) = v;
  }
}

// ---------------- launch (R9 verbatim — green) ----------------
extern "C" void kernel_launch(void* const* d_in, const int* in_sizes, int n_in,
                              void* d_out, int out_size, void* d_ws, size_t ws_size,
                              hipStream_t stream)
{
  const float* query = (const float*)d_in[0];
  const float* key   = (const float*)d_in[1];
  const float* value = (const float*)d_in[2];
  const float* q_w   = (const float*)d_in[3];
  const float* q_b   = (const float*)d_in[4];
  const float* k_w   = (const float*)d_in[5];
  const float* k_b   = (const float*)d_in[6];
  const float* v_w   = (const float*)d_in[7];
  const float* v_b   = (const float*)d_in[8];
  const float* o_w   = (const float*)d_in[9];
  const float* o_b   = (const float*)d_in[10];
  float* out = (float*)d_out;

  char* ws = (char*)d_ws;
  short* q_wb = (short*)(ws);
  short* k_wb = (short*)(ws + 8388608);
  short* v_wb = (short*)(ws + 10485760);
  short* o_wb = (short*)(ws + 12582912);
  short* R1   = (short*)(ws + 20971520);   // kx -> qx -> Ap
  short* R2   = (short*)(ws + 37748736);   // vx -> Qp
  short* Kp   = (short*)(ws + 54525952);
  short* Vp   = (short*)(ws + 58720256);

  const float ALPHA_Q = 0.125f * 1.4426950408889634f;  // SCALE * log2(e)

  k_cvt2<<<dim3(4096, 1, 2), 256, 0, stream>>>(q_w, q_wb, o_w, o_wb, 1048576);
  k_cvt2<<<dim3(1024, 1, 2), 256, 0, stream>>>(k_w, k_wb, v_w, v_wb, 262144);
  k_cvt2<<<dim3(8192, 1, 2), 256, 0, stream>>>(key, R1, value, R2, 2097152);

  k_gemm<false, true><<<dim3(4, 32, 2), 256, 0, stream>>>(
      R1, k_wb, k_b, Kp, R2, v_wb, v_b, Vp, 4096, 512, 2048, 1.0f);

  k_cvt<<<8192, 256, 0, stream>>>(query, R1, 2097152);

  k_gemm<false, false><<<dim3(16, 32), 256, 0, stream>>>(
      R1, q_wb, q_b, R2, nullptr, nullptr, nullptr, nullptr, 4096, 2048, 2048, ALPHA_Q);

  k_attn<<<dim3(512), dim3(512), 0, stream>>>(R2, Kp, Vp, R1);

  k_gemm<true, false><<<dim3(16, 32), 256, 0, stream>>>(
      R1, o_wb, o_b, out, nullptr, nullptr, nullptr, nullptr, 4096, 2048, 2048, 1.0f);
}